// Round 11
// baseline (428.569 us; speedup 1.0000x reference)
//
#include <hip/hip_runtime.h>

typedef short sh8 __attribute__((ext_vector_type(8)));
typedef __bf16 bf8 __attribute__((ext_vector_type(8)));
typedef float f4 __attribute__((ext_vector_type(4)));
typedef unsigned int u4 __attribute__((ext_vector_type(4)));

#define DEV __device__ __forceinline__

DEV unsigned int fbits(float f){ union{float f;unsigned int u;}v; v.f=f; return v.u; }
DEV float bitsf(unsigned int u){ union{unsigned int u;float f;}v; v.u=u; return v.f; }
DEV float bf2f(unsigned short u) { return bitsf(((unsigned int)u) << 16); }
// RTNE f32->bf16 (proven numerics — DO NOT CHANGE)
DEV unsigned short f2bf(float f) {
    unsigned int x = fbits(f);
    return (unsigned short)((x + 0x7fffu + ((x >> 16) & 1u)) >> 16);
}
// softplus — branch-free native-op inline (proven rounds 7/8/9 — DO NOT CHANGE)
DEV float sp_f(float x) {
    float ax = fabsf(x);
    float e  = exp2f(ax * -1.4426950408889634f);
    float u  = 1.0f + e;
    float c  = e - (u - 1.0f);
    float lg = log2f(u);
    return fmaxf(x, 0.0f) + fmaf(0.69314718055994531f, lg, c * (2.0f - u));
}

#define MFMA(a, b, c) __builtin_amdgcn_mfma_f32_16x16x32_bf16(__builtin_bit_cast(bf8, a), __builtin_bit_cast(bf8, b), c, 0, 0, 0)

// ---------------- T = einsum(w_mean_norm, bone_transforms) ----------------
__global__ void t_kernel(const float* __restrict__ sw,
                         const float* __restrict__ bt,
                         float* __restrict__ Tout, int V) {
    __shared__ float red[4 * 24];
    __shared__ float mm[24];
    float p[24];
#pragma unroll
    for (int j = 0; j < 24; j++) p[j] = 0.0f;
    for (int v = threadIdx.x; v < V; v += 256) {
        const float* row = sw + v * 24;
#pragma unroll
        for (int c4 = 0; c4 < 6; c4++) {
            f4 a = *(const f4*)(row + c4 * 4);
#pragma unroll
            for (int e = 0; e < 4; e++) p[c4 * 4 + e] += a[e];
        }
    }
#pragma unroll
    for (int j = 0; j < 24; j++) {
#pragma unroll
        for (int msk = 1; msk < 64; msk <<= 1) p[j] += __shfl_xor(p[j], msk);
    }
    int lane = threadIdx.x & 63, wid = threadIdx.x >> 6;
    if (lane == 0) {
#pragma unroll
        for (int j = 0; j < 24; j++) red[wid * 24 + j] = p[j];
    }
    __syncthreads();
    if (threadIdx.x < 24) {
        float s = red[threadIdx.x] + red[24 + threadIdx.x] + red[48 + threadIdx.x] + red[72 + threadIdx.x];
        mm[threadIdx.x] = s / (float)V;
    }
    __syncthreads();
    if (threadIdx.x < 16) {
        float tot = 0.0f;
#pragma unroll
        for (int j = 0; j < 24; j++) tot += mm[j];
        float a = 0.0f;
#pragma unroll
        for (int j = 0; j < 24; j++) a += (mm[j] / tot) * bt[j * 16 + threadIdx.x];
        Tout[threadIdx.x] = a;
    }
}

// ---------------- main: trace + secant + sample ----------------
// 512 threads = 8 waves = 4 ray-groups x 2 K-halves. Wave pair (grp, half):
// both handle the same 16 rays; half h computes ks in {2h, 2h+1} (K-half).
// Partial c exchanged via LDS (each wave epilogues 4 of 8 f-cols), partial pr
// exchanged; s = (prA + prB) + b3 identical in both waves (f32 add commutes).
// All loops run fixed trip counts (no breaks) -> uniform barriers, no deadlock.
__global__ __launch_bounds__(512, 2) void main_kernel(
    const float* __restrict__ cam_loc, const float* __restrict__ dirs,
    const float* __restrict__ bbi,     const float* __restrict__ loc,
    const float* __restrict__ scf,     const float* __restrict__ trans,
    const float* __restrict__ cmin,    const float* __restrict__ cmax,
    const float* __restrict__ cent,    const float* __restrict__ W1,
    const float* __restrict__ b1,      const float* __restrict__ W2,
    const float* __restrict__ b2,      const float* __restrict__ W3,
    const float* __restrict__ b3,      const float* __restrict__ Tmat,
    float* __restrict__ out, int N) {

    __shared__ unsigned short wfrag[3 * 16384];   // 96 KB
    __shared__ f4 red_c[4][2][4][64];             // 32 KB: [grp][half][q][lane]
    __shared__ float red_s[4][2][16];             // 512 B
    __shared__ f4 w1p[16 * 9];                    // stride-9 pad
    __shared__ float b2s[128], w3s[128];

    const int tid = threadIdx.x;

    // ---- stage W2 (f32) -> 3 RTNE splits, fragment order (bit-exact) ----
    for (int i4 = tid; i4 < 4096; i4 += 512) {
        f4 v = *(const f4*)(W2 + i4 * 4);
        int k = (i4 * 4) >> 7;
        int n0 = (i4 * 4) & 127;
        int lanehalf = ((k >> 3) & 3) << 4;
        int fk = k >> 5;
        int j = k & 7;
#pragma unroll
        for (int e = 0; e < 4; e++) {
            int n = n0 + e;
            float w = v[e];
            unsigned short u0 = f2bf(w);   float g0 = bf2f(u0);
            float r1 = w - g0;             unsigned short u1 = f2bf(r1); float g1 = bf2f(u1);
            float r2 = r1 - g1;            unsigned short u2 = f2bf(r2);
            int off = ((n >> 4) * 4 + fk) * 512 + (lanehalf | (n & 15)) * 8 + j;
            wfrag[off]         = u0;
            wfrag[16384 + off] = u1;
            wfrag[32768 + off] = u2;
        }
    }
    if (tid < 128) {
        int k = tid, ks = k >> 5, uu = (k >> 3) & 3, j = k & 7;
        f4 w;
        w.x = W1[k]; w.y = W1[128 + k]; w.z = W1[256 + k]; w.w = b1[k];
        w1p[(ks * 4 + uu) * 9 + j] = w;
        b2s[k] = b2[k];
        w3s[k] = W3[k];
    }
    __syncthreads();

    const int lane = tid & 63;
    const int wv = tid >> 6;      // 0..7
    const int grp = wv >> 1;      // ray group 0..3
    const int half = wv & 1;      // K-half 0/1
    const int m = lane & 15, u = lane >> 4;
    const int rayBase = (blockIdx.x * 4 + grp) * 16;
    const int R = rayBase + m;

    const int O1 = 3 * N, O2 = 4 * N, O3 = 5 * N, O4 = 101 * N, O5 = 133 * N, O6 = 645 * N;

    float camx = cam_loc[0], camy = cam_loc[1], camz = cam_loc[2];
    float A[3], Bc[3];
#pragma unroll
    for (int c = 0; c < 3; c++) {
        float he = 0.5f * (cmax[c] - cmin[c]);
        float sc = scf[c];
        float off = (0.0f - trans[c] - loc[c]) * sc - cent[c];
        A[c] = sc / he; Bc[c] = off / he;
    }
    float dx = dirs[R * 3 + 0], dy = dirs[R * 3 + 1], dz = dirs[R * 3 + 2];
    float nearv = bbi[R * 2 + 0], farv = bbi[R * 2 + 1];

    // my 4 f-columns' W3; b2 init only for half 0 (added exactly once)
    float w3q[4];
#pragma unroll
    for (int q = 0; q < 4; q++) w3q[q] = w3s[(half * 4 + q) * 16 + m];
    float b2v[8];
#pragma unroll
    for (int f = 0; f < 8; f++) b2v[f] = half ? 0.0f : b2s[f * 16 + m];
    float b3v = b3[0];

    const int lane16 = lane * 8;

    // ---- one SDF eval at t; returns s (identical bits in both waves) ----
    auto EVAL = [&](float t, float& sout) {
        float y0 = fmaf(t, dx, camx), y1 = fmaf(t, dy, camy), y2 = fmaf(t, dz, camz);
        float x0 = fmaf(y0, A[0], Bc[0]), x1 = fmaf(y1, A[1], Bc[1]), x2 = fmaf(y2, A[2], Bc[2]);
        f4 c[8];
#pragma unroll
        for (int f = 0; f < 8; f++) {
            float b = b2v[f];
            c[f] = (f4){b, b, b, b};
        }
#pragma unroll 1
        for (int ks2 = 0; ks2 < 2; ks2++) {
            const int ks = half * 2 + ks2;
            u4 a0w, a1w, a2w;
#pragma unroll
            for (int jp = 0; jp < 4; jp++) {
                f4 wA = w1p[(ks * 4 + u) * 9 + 2 * jp];
                f4 wB = w1p[(ks * 4 + u) * 9 + 2 * jp + 1];
                float hA = fmaf(x0, wA.x, fmaf(x1, wA.y, fmaf(x2, wA.z, wA.w)));
                float hB = fmaf(x0, wB.x, fmaf(x1, wB.y, fmaf(x2, wB.z, wB.w)));
                float sA = sp_f(hA), sB = sp_f(hB);
                unsigned short A0 = f2bf(sA); float fA0 = bf2f(A0);
                unsigned short B0 = f2bf(sB); float fB0 = bf2f(B0);
                float rA1 = sA - fA0, rB1 = sB - fB0;
                unsigned short A1 = f2bf(rA1); float fA1 = bf2f(A1);
                unsigned short B1 = f2bf(rB1); float fB1 = bf2f(B1);
                float rA2 = rA1 - fA1, rB2 = rB1 - fB1;
                unsigned short A2 = f2bf(rA2);
                unsigned short B2 = f2bf(rB2);
                a0w[jp] = (unsigned int)A0 | ((unsigned int)B0 << 16);
                a1w[jp] = (unsigned int)A1 | ((unsigned int)B1 << 16);
                a2w[jp] = (unsigned int)A2 | ((unsigned int)B2 << 16);
            }
            const int base = ks * 512 + lane16;
#pragma unroll
            for (int f = 0; f < 8; f++) {
                int fi = f * 2048 + base;
                sh8 b0 = *(const sh8*)&wfrag[fi];
                sh8 b1f = *(const sh8*)&wfrag[16384 + fi];
                sh8 b2f = *(const sh8*)&wfrag[32768 + fi];
                c[f] = MFMA(a0w, b0, c[f]);
                c[f] = MFMA(a1w, b0, c[f]);
                c[f] = MFMA(a2w, b0, c[f]);
                c[f] = MFMA(a0w, b1f, c[f]);
                c[f] = MFMA(a1w, b1f, c[f]);
                c[f] = MFMA(a0w, b2f, c[f]);
            }
        }
        // exchange partial c for the partner's f-range
#pragma unroll
        for (int q = 0; q < 4; q++)
            red_c[grp][half][q][lane] = c[(1 - half) * 4 + q];
        __syncthreads();
        // combine my f-range, epilogue on 4 f's
        float pr0 = 0.f, pr1 = 0.f, pr2 = 0.f, pr3 = 0.f;
#pragma unroll
        for (int q = 0; q < 4; q++) {
            f4 cc = c[half * 4 + q] + red_c[grp][1 - half][q][lane];
            float wv3 = w3q[q];
            pr0 = fmaf(sp_f(cc.x), wv3, pr0);
            pr1 = fmaf(sp_f(cc.y), wv3, pr1);
            pr2 = fmaf(sp_f(cc.z), wv3, pr2);
            pr3 = fmaf(sp_f(cc.w), wv3, pr3);
        }
        // reduce over the 16 m-lanes
#pragma unroll
        for (int msk = 1; msk < 16; msk <<= 1) {
            pr0 += __shfl_xor(pr0, msk); pr1 += __shfl_xor(pr1, msk);
            pr2 += __shfl_xor(pr2, msk); pr3 += __shfl_xor(pr3, msk);
        }
        // exchange partial pr (ray r=u*4+m holds component m for m<4)
        float prm = (m == 0) ? pr0 : (m == 1) ? pr1 : (m == 2) ? pr2 : pr3;
        if (m < 4) red_s[grp][half][u * 4 + m] = prm;
        __syncthreads();
        float oth = red_s[grp][1 - half][m];
        int srcl = (m >> 2) << 4;
        float q0 = __shfl(pr0, srcl), q1 = __shfl(pr1, srcl);
        float q2 = __shfl(pr2, srcl), q3 = __shfl(pr3, srcl);
        float sa = (m & 1) ? q1 : q0, sb = (m & 1) ? q3 : q2;
        float mine = (m & 2) ? sb : sa;
        sout = (mine + oth) + b3v;
    };

    // ---- sphere tracing (fixed 32 iters; updates mask-gated) ----
    float acc = nearv;
    bool unf = nearv < farv;
    bool dv = !unf;
    float sv;
#pragma unroll 1
    for (int it = 0; it < 32; ++it) {
        EVAL(acc, sv);
        float smv = fminf(fmaxf(sv, -0.1f), 0.1f);
        bool convu = unf;
        bool upd = unf && (fabsf(smv) > 1e-5f) && (fabsf(sv) < 1000000.0f);
        if (upd) acc = acc + smv;
        dv = upd ? (acc >= farv) : dv;
        bool remove = (convu && (fabsf(sv) <= 1e-5f)) || dv;
        unf = unf && !remove;
    }

    // ---- secant (last iteration is the final eval) ----
    float t0 = fminf(fmaxf(acc - 0.1f, nearv), farv);
    float t1 = fminf(fmaxf(acc, nearv), farv);
    float f0;
    EVAL(t0, f0);
    float f1 = 0.0f;
#pragma unroll 1
    for (int si = 0; si < 9; ++si) {
        float f1s;
        EVAL(t1, f1s);
        if (si == 8) { f1 = f1s; break; }
        float den = f0 - f1s;
        den = (fabsf(den) < 1e-9f) ? 1e-9f : den;
        float t2 = t1 - f1s * (t1 - t0) / den;
        t2 = fminf(fmaxf(t2, nearv), farv);
        t0 = t1; f0 = f1s; t1 = t2;
    }
    bool conv = (fabsf(f1) <= 1e-5f) && (t1 >= nearv) && (t1 <= farv);

    // xn at t1 (bit-identical to EVAL's internal xn)
    float xv0, xv1, xv2;
    {
        float y0 = fmaf(t1, dx, camx), y1 = fmaf(t1, dy, camy), y2 = fmaf(t1, dz, camz);
        xv0 = fmaf(y0, A[0], Bc[0]); xv1 = fmaf(y1, A[1], Bc[1]); xv2 = fmaf(y2, A[2], Bc[2]);
    }

    if (u == 0 && half == 0) {
        out[R * 3 + 0] = xv0;
        out[R * 3 + 1] = xv1;
        out[R * 3 + 2] = xv2;
        out[O1 + R] = conv ? 1.0f : 0.0f;
        out[O2 + R] = conv ? t1 : nearv;
        out[O6 + R] = conv ? 1.0f : 0.0f;
    }

    if (half == 0) {
        // ---- z samples: merge(sorted z_near, sorted z_far) if conv, else uniform ----
        float zreg[8];
        if (conv) {
            float a0v = t1 - 0.05f, sa = 0.1f / 15.0f;
            float b0v = nearv, sb = (farv - nearv) / 15.0f;
            int ia = 0, ib = 0;
#pragma unroll
            for (int i = 0; i < 32; i++) {
                float va = fmaf((float)ia, sa, a0v);
                float vb = fmaf((float)ib, sb, b0v);
                bool ta = (ia < 16) && ((ib >= 16) || (va <= vb));
                float zv = ta ? va : vb;
                if (ta) ia++; else ib++;
                if ((i >> 3) == u) zreg[i & 7] = zv;
            }
        } else {
            float rng = farv - nearv;
#pragma unroll
            for (int q = 0; q < 8; q++) {
                int i = u * 8 + q;
                zreg[q] = fmaf((float)i * (1.0f / 31.0f), rng, nearv);
            }
        }
        // dists
        {
            f4 d0, d1;
#pragma unroll
            for (int q = 0; q < 4; q++) { d0[q] = zreg[q]; d1[q] = zreg[4 + q]; }
            *(f4*)&out[O4 + R * 32 + u * 8] = d0;
            *(f4*)&out[O4 + R * 32 + u * 8 + 4] = d1;
        }
        // points
        {
            f4 pk[6];
#pragma unroll
            for (int q = 0; q < 8; q++) {
                float z = zreg[q];
                float y0 = fmaf(z, dx, camx), y1 = fmaf(z, dy, camy), y2 = fmaf(z, dz, camz);
                float v0 = fmaf(y0, A[0], Bc[0]);
                float v1 = fmaf(y1, A[1], Bc[1]);
                float v2 = fmaf(y2, A[2], Bc[2]);
#pragma unroll
                for (int c = 0; c < 3; c++) {
                    int ee = q * 3 + c;
                    float vv = (c == 0) ? v0 : ((c == 1) ? v1 : v2);
                    pk[ee >> 2][ee & 3] = vv;
                }
            }
            int pbase = O3 + R * 96 + u * 24;
#pragma unroll
            for (int s6 = 0; s6 < 6; s6++) *(f4*)&out[pbase + s6 * 4] = pk[s6];
        }
    }

    // ---- sampler_transforms: broadcast T rows, split between wave pair ----
    {
        f4 myrow = *(const f4*)&Tmat[(lane & 3) * 4];
        int base = O5 + rayBase * 512;
        int cb = half ? 8 : 0, ce = half ? 32 : 8;
        for (int cc = cb; cc < ce; cc++) {
            int g = lane + 64 * cc;
            *(f4*)&out[base + g * 4] = myrow;
        }
    }
}

extern "C" void kernel_launch(void* const* d_in, const int* in_sizes, int n_in,
                              void* d_out, int out_size, void* d_ws, size_t ws_size,
                              hipStream_t stream) {
    (void)n_in; (void)out_size; (void)ws_size;
    const float* cam  = (const float*)d_in[0];
    const float* dirs = (const float*)d_in[1];
    const float* bbi  = (const float*)d_in[2];
    const float* loc  = (const float*)d_in[3];
    const float* scf  = (const float*)d_in[4];
    const float* sw   = (const float*)d_in[7];
    const float* bt   = (const float*)d_in[8];
    const float* trn  = (const float*)d_in[9];
    const float* cmn  = (const float*)d_in[10];
    const float* cmx  = (const float*)d_in[11];
    const float* cen  = (const float*)d_in[12];
    const float* W1   = (const float*)d_in[13];
    const float* b1   = (const float*)d_in[14];
    const float* W2   = (const float*)d_in[15];
    const float* b2   = (const float*)d_in[16];
    const float* W3   = (const float*)d_in[17];
    const float* b3   = (const float*)d_in[18];

    float* Tout = (float*)d_ws;
    int N = in_sizes[1] / 3;
    int V = in_sizes[7] / 24;

    hipLaunchKernelGGL(t_kernel, dim3(1), dim3(256), 0, stream, sw, bt, Tout, V);
    hipLaunchKernelGGL(main_kernel, dim3(N / 64), dim3(512), 0, stream,
                       cam, dirs, bbi, loc, scf, trn, cmn, cmx, cen,
                       W1, b1, W2, b2, W3, b3, Tout,
                       (float*)d_out, N);
}

// Round 12
// 366.544 us; speedup vs baseline: 1.1692x; 1.1692x over previous
//
#include <hip/hip_runtime.h>

typedef short sh8 __attribute__((ext_vector_type(8)));
typedef __bf16 bf8 __attribute__((ext_vector_type(8)));
typedef float f4 __attribute__((ext_vector_type(4)));
typedef unsigned int u4 __attribute__((ext_vector_type(4)));

#define DEV __device__ __forceinline__

DEV unsigned int fbits(float f){ union{float f;unsigned int u;}v; v.f=f; return v.u; }
DEV float bitsf(unsigned int u){ union{unsigned int u;float f;}v; v.u=u; return v.f; }
DEV float bf2f(unsigned short u) { return bitsf(((unsigned int)u) << 16); }
// RTNE f32->bf16 (proven numerics — DO NOT CHANGE)
DEV unsigned short f2bf(float f) {
    unsigned int x = fbits(f);
    return (unsigned short)((x + 0x7fffu + ((x >> 16) & 1u)) >> 16);
}
// softplus — branch-free native-op inline (proven rounds 7/8/9 — DO NOT CHANGE)
DEV float sp_f(float x) {
    float ax = fabsf(x);
    float e  = exp2f(ax * -1.4426950408889634f);
    float u  = 1.0f + e;
    float c  = e - (u - 1.0f);
    float lg = log2f(u);
    return fmaxf(x, 0.0f) + fmaf(0.69314718055994531f, lg, c * (2.0f - u));
}

#define MFMA(a, b, c) __builtin_amdgcn_mfma_f32_16x16x32_bf16(__builtin_bit_cast(bf8, a), __builtin_bit_cast(bf8, b), c, 0, 0, 0)

// ---------------- T = einsum(w_mean_norm, bone_transforms) ----------------
__global__ void t_kernel(const float* __restrict__ sw,
                         const float* __restrict__ bt,
                         float* __restrict__ Tout, int V) {
    __shared__ float red[4 * 24];
    __shared__ float mm[24];
    float p[24];
#pragma unroll
    for (int j = 0; j < 24; j++) p[j] = 0.0f;
    for (int v = threadIdx.x; v < V; v += 256) {
        const float* row = sw + v * 24;
#pragma unroll
        for (int c4 = 0; c4 < 6; c4++) {
            f4 a = *(const f4*)(row + c4 * 4);
#pragma unroll
            for (int e = 0; e < 4; e++) p[c4 * 4 + e] += a[e];
        }
    }
#pragma unroll
    for (int j = 0; j < 24; j++) {
#pragma unroll
        for (int msk = 1; msk < 64; msk <<= 1) p[j] += __shfl_xor(p[j], msk);
    }
    int lane = threadIdx.x & 63, wid = threadIdx.x >> 6;
    if (lane == 0) {
#pragma unroll
        for (int j = 0; j < 24; j++) red[wid * 24 + j] = p[j];
    }
    __syncthreads();
    if (threadIdx.x < 24) {
        float s = red[threadIdx.x] + red[24 + threadIdx.x] + red[48 + threadIdx.x] + red[72 + threadIdx.x];
        mm[threadIdx.x] = s / (float)V;
    }
    __syncthreads();
    if (threadIdx.x < 16) {
        float tot = 0.0f;
#pragma unroll
        for (int j = 0; j < 24; j++) tot += mm[j];
        float a = 0.0f;
#pragma unroll
        for (int j = 0; j < 24; j++) a += (mm[j] / tot) * bt[j * 16 + threadIdx.x];
        Tout[threadIdx.x] = a;
    }
}

// ---------------- main: trace + secant + sample ----------------
// 512 threads = 8 waves = 4 ray-groups x 2 K-halves. Wave pair (grp, half):
// both handle the same 16 rays; half h computes ks in {2h, 2h+1} (K-half).
// Accumulators cL[4] (f=0..3) / cH[4] (f=4..7) are STATICALLY indexed
// (rule #20: runtime-indexed arrays go to scratch — round 11's bug).
// Partial c exchanged via LDS (each wave epilogues 4 of 8 f-cols), partial pr
// exchanged; s = (prA + prB) + b3 identical in both waves (f32 add commutes).
// All loops run fixed trip counts (no breaks) -> uniform barriers, no deadlock.
__global__ __launch_bounds__(512, 2) void main_kernel(
    const float* __restrict__ cam_loc, const float* __restrict__ dirs,
    const float* __restrict__ bbi,     const float* __restrict__ loc,
    const float* __restrict__ scf,     const float* __restrict__ trans,
    const float* __restrict__ cmin,    const float* __restrict__ cmax,
    const float* __restrict__ cent,    const float* __restrict__ W1,
    const float* __restrict__ b1,      const float* __restrict__ W2,
    const float* __restrict__ b2,      const float* __restrict__ W3,
    const float* __restrict__ b3,      const float* __restrict__ Tmat,
    float* __restrict__ out, int N) {

    __shared__ unsigned short wfrag[3 * 16384];   // 96 KB
    __shared__ f4 red_c[4][2][4][64];             // 32 KB: [grp][half][q][lane]
    __shared__ float red_s[4][2][16];             // 512 B
    __shared__ f4 w1p[16 * 9];                    // stride-9 pad
    __shared__ float b2s[128], w3s[128];

    const int tid = threadIdx.x;

    // ---- stage W2 (f32) -> 3 RTNE splits, fragment order (bit-exact) ----
    for (int i4 = tid; i4 < 4096; i4 += 512) {
        f4 v = *(const f4*)(W2 + i4 * 4);
        int k = (i4 * 4) >> 7;
        int n0 = (i4 * 4) & 127;
        int lanehalf = ((k >> 3) & 3) << 4;
        int fk = k >> 5;
        int j = k & 7;
#pragma unroll
        for (int e = 0; e < 4; e++) {
            int n = n0 + e;
            float w = v[e];
            unsigned short u0 = f2bf(w);   float g0 = bf2f(u0);
            float r1 = w - g0;             unsigned short u1 = f2bf(r1); float g1 = bf2f(u1);
            float r2 = r1 - g1;            unsigned short u2 = f2bf(r2);
            int off = ((n >> 4) * 4 + fk) * 512 + (lanehalf | (n & 15)) * 8 + j;
            wfrag[off]         = u0;
            wfrag[16384 + off] = u1;
            wfrag[32768 + off] = u2;
        }
    }
    if (tid < 128) {
        int k = tid, ks = k >> 5, uu = (k >> 3) & 3, j = k & 7;
        f4 w;
        w.x = W1[k]; w.y = W1[128 + k]; w.z = W1[256 + k]; w.w = b1[k];
        w1p[(ks * 4 + uu) * 9 + j] = w;
        b2s[k] = b2[k];
        w3s[k] = W3[k];
    }
    __syncthreads();

    const int lane = tid & 63;
    const int wv = tid >> 6;      // 0..7
    const int grp = wv >> 1;      // ray group 0..3
    const int half = wv & 1;      // K-half 0/1
    const int m = lane & 15, u = lane >> 4;
    const int rayBase = (blockIdx.x * 4 + grp) * 16;
    const int R = rayBase + m;

    const int O1 = 3 * N, O2 = 4 * N, O3 = 5 * N, O4 = 101 * N, O5 = 133 * N, O6 = 645 * N;

    float camx = cam_loc[0], camy = cam_loc[1], camz = cam_loc[2];
    float A[3], Bc[3];
#pragma unroll
    for (int c = 0; c < 3; c++) {
        float he = 0.5f * (cmax[c] - cmin[c]);
        float sc = scf[c];
        float off = (0.0f - trans[c] - loc[c]) * sc - cent[c];
        A[c] = sc / he; Bc[c] = off / he;
    }
    float dx = dirs[R * 3 + 0], dy = dirs[R * 3 + 1], dz = dirs[R * 3 + 2];
    float nearv = bbi[R * 2 + 0], farv = bbi[R * 2 + 1];

    // my 4 f-columns' W3; b2 init only for half 0 (added exactly once)
    float w3q[4];
#pragma unroll
    for (int q = 0; q < 4; q++) w3q[q] = w3s[(half * 4 + q) * 16 + m];
    float b2L[4], b2H[4];
#pragma unroll
    for (int q = 0; q < 4; q++) {
        b2L[q] = half ? 0.0f : b2s[q * 16 + m];
        b2H[q] = half ? 0.0f : b2s[(4 + q) * 16 + m];
    }
    float b3v = b3[0];

    const int lane16 = lane * 8;

    // ---- one SDF eval at t; returns s (identical bits in both waves) ----
    auto EVAL = [&](float t, float& sout) {
        float y0 = fmaf(t, dx, camx), y1 = fmaf(t, dy, camy), y2 = fmaf(t, dz, camz);
        float x0 = fmaf(y0, A[0], Bc[0]), x1 = fmaf(y1, A[1], Bc[1]), x2 = fmaf(y2, A[2], Bc[2]);
        f4 cL[4], cH[4];
#pragma unroll
        for (int q = 0; q < 4; q++) {
            float bl = b2L[q], bh = b2H[q];
            cL[q] = (f4){bl, bl, bl, bl};
            cH[q] = (f4){bh, bh, bh, bh};
        }
#pragma unroll 1
        for (int ks2 = 0; ks2 < 2; ks2++) {
            const int ks = half * 2 + ks2;
            u4 a0w, a1w, a2w;
#pragma unroll
            for (int jp = 0; jp < 4; jp++) {
                f4 wA = w1p[(ks * 4 + u) * 9 + 2 * jp];
                f4 wB = w1p[(ks * 4 + u) * 9 + 2 * jp + 1];
                float hA = fmaf(x0, wA.x, fmaf(x1, wA.y, fmaf(x2, wA.z, wA.w)));
                float hB = fmaf(x0, wB.x, fmaf(x1, wB.y, fmaf(x2, wB.z, wB.w)));
                float sA = sp_f(hA), sB = sp_f(hB);
                unsigned short A0 = f2bf(sA); float fA0 = bf2f(A0);
                unsigned short B0 = f2bf(sB); float fB0 = bf2f(B0);
                float rA1 = sA - fA0, rB1 = sB - fB0;
                unsigned short A1 = f2bf(rA1); float fA1 = bf2f(A1);
                unsigned short B1 = f2bf(rB1); float fB1 = bf2f(B1);
                float rA2 = rA1 - fA1, rB2 = rB1 - fB1;
                unsigned short A2 = f2bf(rA2);
                unsigned short B2 = f2bf(rB2);
                a0w[jp] = (unsigned int)A0 | ((unsigned int)B0 << 16);
                a1w[jp] = (unsigned int)A1 | ((unsigned int)B1 << 16);
                a2w[jp] = (unsigned int)A2 | ((unsigned int)B2 << 16);
            }
            const int base = ks * 512 + lane16;
#pragma unroll
            for (int q = 0; q < 4; q++) {
                int fi = q * 2048 + base;
                sh8 b0 = *(const sh8*)&wfrag[fi];
                sh8 b1f = *(const sh8*)&wfrag[16384 + fi];
                sh8 b2f = *(const sh8*)&wfrag[32768 + fi];
                cL[q] = MFMA(a0w, b0, cL[q]);
                cL[q] = MFMA(a1w, b0, cL[q]);
                cL[q] = MFMA(a2w, b0, cL[q]);
                cL[q] = MFMA(a0w, b1f, cL[q]);
                cL[q] = MFMA(a1w, b1f, cL[q]);
                cL[q] = MFMA(a0w, b2f, cL[q]);
            }
#pragma unroll
            for (int q = 0; q < 4; q++) {
                int fi = (4 + q) * 2048 + base;
                sh8 b0 = *(const sh8*)&wfrag[fi];
                sh8 b1f = *(const sh8*)&wfrag[16384 + fi];
                sh8 b2f = *(const sh8*)&wfrag[32768 + fi];
                cH[q] = MFMA(a0w, b0, cH[q]);
                cH[q] = MFMA(a1w, b0, cH[q]);
                cH[q] = MFMA(a2w, b0, cH[q]);
                cH[q] = MFMA(a0w, b1f, cH[q]);
                cH[q] = MFMA(a1w, b1f, cH[q]);
                cH[q] = MFMA(a0w, b2f, cH[q]);
            }
        }
        // exchange the partner's f-range (wave-uniform branch, static indices)
        if (half == 0) {
#pragma unroll
            for (int q = 0; q < 4; q++) red_c[grp][0][q][lane] = cH[q];
        } else {
#pragma unroll
            for (int q = 0; q < 4; q++) red_c[grp][1][q][lane] = cL[q];
        }
        __syncthreads();
        // combine my f-range, epilogue on 4 f's
        float pr0 = 0.f, pr1 = 0.f, pr2 = 0.f, pr3 = 0.f;
#pragma unroll
        for (int q = 0; q < 4; q++) {
            f4 mine = half ? cH[q] : cL[q];     // q static -> register select
            f4 cc = mine + red_c[grp][1 - half][q][lane];
            float wv3 = w3q[q];
            pr0 = fmaf(sp_f(cc.x), wv3, pr0);
            pr1 = fmaf(sp_f(cc.y), wv3, pr1);
            pr2 = fmaf(sp_f(cc.z), wv3, pr2);
            pr3 = fmaf(sp_f(cc.w), wv3, pr3);
        }
        // reduce over the 16 m-lanes
#pragma unroll
        for (int msk = 1; msk < 16; msk <<= 1) {
            pr0 += __shfl_xor(pr0, msk); pr1 += __shfl_xor(pr1, msk);
            pr2 += __shfl_xor(pr2, msk); pr3 += __shfl_xor(pr3, msk);
        }
        // exchange partial pr (ray r=u*4+m holds component m for m<4)
        float prm = (m == 0) ? pr0 : (m == 1) ? pr1 : (m == 2) ? pr2 : pr3;
        if (m < 4) red_s[grp][half][u * 4 + m] = prm;
        __syncthreads();
        float oth = red_s[grp][1 - half][m];
        int srcl = (m >> 2) << 4;
        float q0 = __shfl(pr0, srcl), q1 = __shfl(pr1, srcl);
        float q2 = __shfl(pr2, srcl), q3 = __shfl(pr3, srcl);
        float sa = (m & 1) ? q1 : q0, sb = (m & 1) ? q3 : q2;
        float mine = (m & 2) ? sb : sa;
        sout = (mine + oth) + b3v;
    };

    // ---- sphere tracing (fixed 32 iters; updates mask-gated) ----
    float acc = nearv;
    bool unf = nearv < farv;
    bool dv = !unf;
    float sv;
#pragma unroll 1
    for (int it = 0; it < 32; ++it) {
        EVAL(acc, sv);
        float smv = fminf(fmaxf(sv, -0.1f), 0.1f);
        bool convu = unf;
        bool upd = unf && (fabsf(smv) > 1e-5f) && (fabsf(sv) < 1000000.0f);
        if (upd) acc = acc + smv;
        dv = upd ? (acc >= farv) : dv;
        bool remove = (convu && (fabsf(sv) <= 1e-5f)) || dv;
        unf = unf && !remove;
    }

    // ---- secant (last iteration is the final eval) ----
    float t0 = fminf(fmaxf(acc - 0.1f, nearv), farv);
    float t1 = fminf(fmaxf(acc, nearv), farv);
    float f0;
    EVAL(t0, f0);
    float f1 = 0.0f;
#pragma unroll 1
    for (int si = 0; si < 9; ++si) {
        float f1s;
        EVAL(t1, f1s);
        if (si == 8) { f1 = f1s; break; }
        float den = f0 - f1s;
        den = (fabsf(den) < 1e-9f) ? 1e-9f : den;
        float t2 = t1 - f1s * (t1 - t0) / den;
        t2 = fminf(fmaxf(t2, nearv), farv);
        t0 = t1; f0 = f1s; t1 = t2;
    }
    bool conv = (fabsf(f1) <= 1e-5f) && (t1 >= nearv) && (t1 <= farv);

    // xn at t1 (bit-identical to EVAL's internal xn)
    float xv0, xv1, xv2;
    {
        float y0 = fmaf(t1, dx, camx), y1 = fmaf(t1, dy, camy), y2 = fmaf(t1, dz, camz);
        xv0 = fmaf(y0, A[0], Bc[0]); xv1 = fmaf(y1, A[1], Bc[1]); xv2 = fmaf(y2, A[2], Bc[2]);
    }

    if (u == 0 && half == 0) {
        out[R * 3 + 0] = xv0;
        out[R * 3 + 1] = xv1;
        out[R * 3 + 2] = xv2;
        out[O1 + R] = conv ? 1.0f : 0.0f;
        out[O2 + R] = conv ? t1 : nearv;
        out[O6 + R] = conv ? 1.0f : 0.0f;
    }

    if (half == 0) {
        // ---- z samples: merge(sorted z_near, sorted z_far) if conv, else uniform ----
        float zreg[8];
        if (conv) {
            float a0v = t1 - 0.05f, sa = 0.1f / 15.0f;
            float b0v = nearv, sb = (farv - nearv) / 15.0f;
            int ia = 0, ib = 0;
#pragma unroll
            for (int i = 0; i < 32; i++) {
                float va = fmaf((float)ia, sa, a0v);
                float vb = fmaf((float)ib, sb, b0v);
                bool ta = (ia < 16) && ((ib >= 16) || (va <= vb));
                float zv = ta ? va : vb;
                if (ta) ia++; else ib++;
                if ((i >> 3) == u) zreg[i & 7] = zv;
            }
        } else {
            float rng = farv - nearv;
#pragma unroll
            for (int q = 0; q < 8; q++) {
                int i = u * 8 + q;
                zreg[q] = fmaf((float)i * (1.0f / 31.0f), rng, nearv);
            }
        }
        // dists
        {
            f4 d0, d1;
#pragma unroll
            for (int q = 0; q < 4; q++) { d0[q] = zreg[q]; d1[q] = zreg[4 + q]; }
            *(f4*)&out[O4 + R * 32 + u * 8] = d0;
            *(f4*)&out[O4 + R * 32 + u * 8 + 4] = d1;
        }
        // points
        {
            f4 pk[6];
#pragma unroll
            for (int q = 0; q < 8; q++) {
                float z = zreg[q];
                float y0 = fmaf(z, dx, camx), y1 = fmaf(z, dy, camy), y2 = fmaf(z, dz, camz);
                float v0 = fmaf(y0, A[0], Bc[0]);
                float v1 = fmaf(y1, A[1], Bc[1]);
                float v2 = fmaf(y2, A[2], Bc[2]);
#pragma unroll
                for (int c = 0; c < 3; c++) {
                    int ee = q * 3 + c;
                    float vv = (c == 0) ? v0 : ((c == 1) ? v1 : v2);
                    pk[ee >> 2][ee & 3] = vv;
                }
            }
            int pbase = O3 + R * 96 + u * 24;
#pragma unroll
            for (int s6 = 0; s6 < 6; s6++) *(f4*)&out[pbase + s6 * 4] = pk[s6];
        }
    }

    // ---- sampler_transforms: broadcast T rows, split between wave pair ----
    {
        f4 myrow = *(const f4*)&Tmat[(lane & 3) * 4];
        int base = O5 + rayBase * 512;
        int cb = half ? 8 : 0, ce = half ? 32 : 8;
        for (int cc = cb; cc < ce; cc++) {
            int g = lane + 64 * cc;
            *(f4*)&out[base + g * 4] = myrow;
        }
    }
}

extern "C" void kernel_launch(void* const* d_in, const int* in_sizes, int n_in,
                              void* d_out, int out_size, void* d_ws, size_t ws_size,
                              hipStream_t stream) {
    (void)n_in; (void)out_size; (void)ws_size;
    const float* cam  = (const float*)d_in[0];
    const float* dirs = (const float*)d_in[1];
    const float* bbi  = (const float*)d_in[2];
    const float* loc  = (const float*)d_in[3];
    const float* scf  = (const float*)d_in[4];
    const float* sw   = (const float*)d_in[7];
    const float* bt   = (const float*)d_in[8];
    const float* trn  = (const float*)d_in[9];
    const float* cmn  = (const float*)d_in[10];
    const float* cmx  = (const float*)d_in[11];
    const float* cen  = (const float*)d_in[12];
    const float* W1   = (const float*)d_in[13];
    const float* b1   = (const float*)d_in[14];
    const float* W2   = (const float*)d_in[15];
    const float* b2   = (const float*)d_in[16];
    const float* W3   = (const float*)d_in[17];
    const float* b3   = (const float*)d_in[18];

    float* Tout = (float*)d_ws;
    int N = in_sizes[1] / 3;
    int V = in_sizes[7] / 24;

    hipLaunchKernelGGL(t_kernel, dim3(1), dim3(256), 0, stream, sw, bt, Tout, V);
    hipLaunchKernelGGL(main_kernel, dim3(N / 64), dim3(512), 0, stream,
                       cam, dirs, bbi, loc, scf, trn, cmn, cmx, cen,
                       W1, b1, W2, b2, W3, b3, Tout,
                       (float*)d_out, N);
}